// Round 1
// baseline (114.249 us; speedup 1.0000x reference)
//
#include <hip/hip_runtime.h>

// ---------------------------------------------------------------------------
// SwitchGLU MoE: out[n] = (silu(x[tok(n)]·Wg[e]^T) * (x[tok(n)]·Wu[e]^T))·Wd[e]^T
// E=8, D=768, H=2048, B=2, S=512, K=2  ->  N = 2048 token-expert pairs.
// Strategy: bucket pairs by expert, grouped bf16-MFMA GEMMs with inline
// fp32->bf16 conversion during LDS staging.
// ---------------------------------------------------------------------------

typedef unsigned short u16;
typedef u16   u16x8  __attribute__((ext_vector_type(8)));
typedef __bf16 bf16x8 __attribute__((ext_vector_type(8)));
typedef float f32x4  __attribute__((ext_vector_type(4)));

#define NE   8
#define DDIM 768
#define HDIM 2048
#define NTOT 2048   // B*S*K
#define TOPK 2

// round-to-nearest-even fp32 -> bf16
__device__ __forceinline__ u16 f2bf(float f) {
  unsigned u = __builtin_bit_cast(unsigned, f);
  unsigned r = (u + 0x7fffu + ((u >> 16) & 1u)) >> 16;
  return (u16)r;
}

__device__ __forceinline__ void cvt16(const float4* p, u16x8& lo, u16x8& hi) {
  float4 f0 = p[0], f1 = p[1], f2 = p[2], f3 = p[3];
  lo[0] = f2bf(f0.x); lo[1] = f2bf(f0.y); lo[2] = f2bf(f0.z); lo[3] = f2bf(f0.w);
  lo[4] = f2bf(f1.x); lo[5] = f2bf(f1.y); lo[6] = f2bf(f1.z); lo[7] = f2bf(f1.w);
  hi[0] = f2bf(f2.x); hi[1] = f2bf(f2.y); hi[2] = f2bf(f2.z); hi[3] = f2bf(f2.w);
  hi[4] = f2bf(f3.x); hi[5] = f2bf(f3.y); hi[6] = f2bf(f3.z); hi[7] = f2bf(f3.w);
}

__device__ __forceinline__ bf16x8 frag(const u16* p) {
  return __builtin_bit_cast(bf16x8, *reinterpret_cast<const u16x8*>(p));
}

__device__ __forceinline__ f32x4 mfma_bf16(bf16x8 a, bf16x8 b, f32x4 c) {
  return __builtin_amdgcn_mfma_f32_16x16x32_bf16(a, b, c, 0, 0, 0);
}

// ---------------------------------------------------------------------------
// Dispatch: bucket token-pairs by expert. One block. Output order within an
// expert is arbitrary (atomics) but the final tensor is order-invariant.
// ---------------------------------------------------------------------------
__global__ void moe_dispatch(const int* __restrict__ idx,
                             int* __restrict__ offs,   // [NE+1]
                             int* __restrict__ perm) { // [NTOT]
  __shared__ int s_cnt[NE];
  __shared__ int s_off[NE + 1];
  __shared__ int s_cur[NE];
  const int tid = threadIdx.x;
  if (tid < NE) { s_cnt[tid] = 0; s_cur[tid] = 0; }
  __syncthreads();
  for (int n = tid; n < NTOT; n += 256) atomicAdd(&s_cnt[idx[n]], 1);
  __syncthreads();
  if (tid == 0) {
    int a = 0;
    for (int e = 0; e < NE; ++e) { s_off[e] = a; a += s_cnt[e]; }
    s_off[NE] = a;
  }
  __syncthreads();
  for (int n = tid; n < NTOT; n += 256) {
    const int e = idx[n];
    const int slot = s_off[e] + atomicAdd(&s_cur[e], 1);
    perm[slot] = n;
  }
  if (tid < NE + 1) offs[tid] = s_off[tid];
}

// ---------------------------------------------------------------------------
// Stage 1: h[row, :] = silu(x·Wg^T) * (x·Wu^T)   (grouped by expert)
// grid = (H/64, 32, E), block = 256 (4 waves, each 32x32 of the 64x64 tile)
// ---------------------------------------------------------------------------
__global__ __launch_bounds__(256) void moe_stage1(
    const float* __restrict__ x, const int* __restrict__ perm,
    const int* __restrict__ offs,
    const float* __restrict__ wg, const float* __restrict__ wu,
    u16* __restrict__ hbuf) {
  const int e = blockIdx.z;
  const int off = offs[e];
  const int cnt = offs[e + 1] - off;
  const int mt = blockIdx.y;
  if (mt * 64 >= cnt) return;
  const int nt = blockIdx.x;

  __shared__ __align__(16) u16 sX[64][72];
  __shared__ __align__(16) u16 sG[64][72];
  __shared__ __align__(16) u16 sU[64][72];

  const int tid = threadIdx.x;
  const int lane = tid & 63;
  const int wv = tid >> 6;
  const int wm = (wv >> 1) * 32;
  const int wn = (wv & 1) * 32;

  const int sr = tid >> 2;         // staging row 0..63
  const int sc = (tid & 3) << 4;   // staging col 0,16,32,48

  const int m = mt * 64 + sr;
  const float* xrow = nullptr;
  if (m < cnt) {
    const int t = perm[off + m];
    xrow = x + (size_t)(t >> 1) * DDIM;  // TOPK = 2
  }
  const float* grow = wg + ((size_t)e * HDIM + (size_t)(nt * 64 + sr)) * DDIM;
  const float* urow = wu + ((size_t)e * HDIM + (size_t)(nt * 64 + sr)) * DDIM;

  f32x4 aG[2][2] = {};
  f32x4 aU[2][2] = {};

  for (int kt = 0; kt < DDIM / 64; ++kt) {
    const int k0 = kt * 64;
    __syncthreads();
    {
      u16x8 lo = {0, 0, 0, 0, 0, 0, 0, 0}, hi = {0, 0, 0, 0, 0, 0, 0, 0};
      if (xrow) cvt16(reinterpret_cast<const float4*>(xrow + k0 + sc), lo, hi);
      *reinterpret_cast<u16x8*>(&sX[sr][sc]) = lo;
      *reinterpret_cast<u16x8*>(&sX[sr][sc + 8]) = hi;
    }
    {
      u16x8 lo, hi;
      cvt16(reinterpret_cast<const float4*>(grow + k0 + sc), lo, hi);
      *reinterpret_cast<u16x8*>(&sG[sr][sc]) = lo;
      *reinterpret_cast<u16x8*>(&sG[sr][sc + 8]) = hi;
      cvt16(reinterpret_cast<const float4*>(urow + k0 + sc), lo, hi);
      *reinterpret_cast<u16x8*>(&sU[sr][sc]) = lo;
      *reinterpret_cast<u16x8*>(&sU[sr][sc + 8]) = hi;
    }
    __syncthreads();
#pragma unroll
    for (int kh = 0; kh < 2; ++kh) {
      const int kc = kh * 32 + ((lane >> 4) << 3);
      const int fr = lane & 15;
      bf16x8 a0 = frag(&sX[wm + fr][kc]);
      bf16x8 a1 = frag(&sX[wm + 16 + fr][kc]);
      bf16x8 g0 = frag(&sG[wn + fr][kc]);
      bf16x8 g1 = frag(&sG[wn + 16 + fr][kc]);
      bf16x8 u0 = frag(&sU[wn + fr][kc]);
      bf16x8 u1 = frag(&sU[wn + 16 + fr][kc]);
      aG[0][0] = mfma_bf16(a0, g0, aG[0][0]);
      aG[0][1] = mfma_bf16(a0, g1, aG[0][1]);
      aG[1][0] = mfma_bf16(a1, g0, aG[1][0]);
      aG[1][1] = mfma_bf16(a1, g1, aG[1][1]);
      aU[0][0] = mfma_bf16(a0, u0, aU[0][0]);
      aU[0][1] = mfma_bf16(a0, u1, aU[0][1]);
      aU[1][0] = mfma_bf16(a1, u0, aU[1][0]);
      aU[1][1] = mfma_bf16(a1, u1, aU[1][1]);
    }
  }

  // epilogue: C/D layout col=lane&15, row=(lane>>4)*4+reg  [m89/m91]
  const int crow = (lane >> 4) << 2;
  const int ccol = lane & 15;
#pragma unroll
  for (int mi = 0; mi < 2; ++mi) {
#pragma unroll
    for (int r = 0; r < 4; ++r) {
      const int gm = mt * 64 + wm + mi * 16 + crow + r;
      if (gm < cnt) {
        u16* hrow = hbuf + (size_t)(off + gm) * HDIM + (size_t)(nt * 64 + wn);
#pragma unroll
        for (int ni = 0; ni < 2; ++ni) {
          const float g = aG[mi][ni][r];
          const float u = aU[mi][ni][r];
          const float h = g / (1.0f + __expf(-g)) * u;
          hrow[ni * 16 + ccol] = f2bf(h);
        }
      }
    }
  }
}

// ---------------------------------------------------------------------------
// Stage 2: out[perm[row], :] = h[row, :]·Wd[e]^T
// grid = (D/64, 32, E), block = 256
// ---------------------------------------------------------------------------
__global__ __launch_bounds__(256) void moe_stage2(
    const u16* __restrict__ hbuf, const int* __restrict__ perm,
    const int* __restrict__ offs, const float* __restrict__ wd,
    float* __restrict__ out) {
  const int e = blockIdx.z;
  const int off = offs[e];
  const int cnt = offs[e + 1] - off;
  const int mt = blockIdx.y;
  if (mt * 64 >= cnt) return;
  const int nt = blockIdx.x;  // 0..11

  __shared__ __align__(16) u16 sA[64][72];
  __shared__ __align__(16) u16 sB[64][72];

  const int tid = threadIdx.x;
  const int lane = tid & 63;
  const int wv = tid >> 6;
  const int wm = (wv >> 1) * 32;
  const int wn = (wv & 1) * 32;

  const int sr = tid >> 2;
  const int sc = (tid & 3) << 4;

  const int m = mt * 64 + sr;
  const u16* arow = (m < cnt) ? (hbuf + (size_t)(off + m) * HDIM) : nullptr;
  const float* brow = wd + ((size_t)e * DDIM + (size_t)(nt * 64 + sr)) * HDIM;

  f32x4 acc[2][2] = {};

  for (int kt = 0; kt < HDIM / 64; ++kt) {
    const int k0 = kt * 64;
    __syncthreads();
    {
      u16x8 lo = {0, 0, 0, 0, 0, 0, 0, 0}, hi = {0, 0, 0, 0, 0, 0, 0, 0};
      if (arow) {
        const u16x8* p = reinterpret_cast<const u16x8*>(arow + k0 + sc);
        lo = p[0];
        hi = p[1];
      }
      *reinterpret_cast<u16x8*>(&sA[sr][sc]) = lo;
      *reinterpret_cast<u16x8*>(&sA[sr][sc + 8]) = hi;
    }
    {
      u16x8 lo, hi;
      cvt16(reinterpret_cast<const float4*>(brow + k0 + sc), lo, hi);
      *reinterpret_cast<u16x8*>(&sB[sr][sc]) = lo;
      *reinterpret_cast<u16x8*>(&sB[sr][sc + 8]) = hi;
    }
    __syncthreads();
#pragma unroll
    for (int kh = 0; kh < 2; ++kh) {
      const int kc = kh * 32 + ((lane >> 4) << 3);
      const int fr = lane & 15;
      bf16x8 a0 = frag(&sA[wm + fr][kc]);
      bf16x8 a1 = frag(&sA[wm + 16 + fr][kc]);
      bf16x8 b0 = frag(&sB[wn + fr][kc]);
      bf16x8 b1 = frag(&sB[wn + 16 + fr][kc]);
      acc[0][0] = mfma_bf16(a0, b0, acc[0][0]);
      acc[0][1] = mfma_bf16(a0, b1, acc[0][1]);
      acc[1][0] = mfma_bf16(a1, b0, acc[1][0]);
      acc[1][1] = mfma_bf16(a1, b1, acc[1][1]);
    }
  }

  const int crow = (lane >> 4) << 2;
  const int ccol = lane & 15;
#pragma unroll
  for (int mi = 0; mi < 2; ++mi) {
#pragma unroll
    for (int r = 0; r < 4; ++r) {
      const int gm = mt * 64 + wm + mi * 16 + crow + r;
      if (gm < cnt) {
        const int t = perm[off + gm];
        float* orow = out + (size_t)t * DDIM + (size_t)(nt * 64 + wn);
#pragma unroll
        for (int ni = 0; ni < 2; ++ni) {
          orow[ni * 16 + ccol] = acc[mi][ni][r];
        }
      }
    }
  }
}

// ---------------------------------------------------------------------------
extern "C" void kernel_launch(void* const* d_in, const int* in_sizes, int n_in,
                              void* d_out, int out_size, void* d_ws, size_t ws_size,
                              hipStream_t stream) {
  const float* x  = (const float*)d_in[0];
  const int* idx  = (const int*)d_in[1];
  const float* wg = (const float*)d_in[2];
  const float* wu = (const float*)d_in[3];
  const float* wd = (const float*)d_in[4];
  float* out = (float*)d_out;

  // workspace layout: [offs(9) pad to 16][perm(2048)] ints, then bf16 h buffer
  int* iws = (int*)d_ws;
  int* offs = iws;             // 9 ints
  int* perm = iws + 16;        // 2048 ints
  u16* hbuf = (u16*)((char*)d_ws + 16384);  // NTOT*HDIM bf16 = 8 MB

  moe_dispatch<<<1, 256, 0, stream>>>(idx, offs, perm);
  moe_stage1<<<dim3(HDIM / 64, 32, NE), 256, 0, stream>>>(x, perm, offs, wg, wu, hbuf);
  moe_stage2<<<dim3(DDIM / 64, 32, NE), 256, 0, stream>>>(hbuf, perm, offs, wd, out);
}

// Round 2
// 110.366 us; speedup vs baseline: 1.0352x; 1.0352x over previous
//
#include <hip/hip_runtime.h>

// ---------------------------------------------------------------------------
// SwitchGLU MoE, round 2: pipelined grouped bf16-MFMA GEMMs.
//  - 2-deep register prefetch + double-buffered XOR-swizzled LDS
//  - cheap fp32->bf16 pack (add 0x8000 + v_perm_b32)
//  - stage2 split-K=2 with deterministic fp32 atomicAdd (2 addends commute)
// ---------------------------------------------------------------------------

typedef unsigned short u16;
typedef unsigned int   u32;
typedef u16   u16x8 __attribute__((ext_vector_type(8)));
typedef u32   u32x4 __attribute__((ext_vector_type(4)));
typedef __bf16 bf16x8 __attribute__((ext_vector_type(8)));
typedef float f32x4 __attribute__((ext_vector_type(4)));

#define NE   8
#define DDIM 768
#define HDIM 2048
#define NTOT 2048

// pack two fp32 -> dword of two bf16 (round-half-away-from-zero, <=0.5 ulp)
__device__ __forceinline__ u32 pack2(float a, float b) {
  u32 ua = __builtin_bit_cast(u32, a) + 0x8000u;
  u32 ub = __builtin_bit_cast(u32, b) + 0x8000u;
  return __builtin_amdgcn_perm(ub, ua, 0x07060302);  // low u16 = bf16(a)
}

__device__ __forceinline__ u16 f2bf(float f) {
  return (u16)((__builtin_bit_cast(u32, f) + 0x8000u) >> 16);
}

// swizzled u16 offset of 8-element chunk c (0..3) in row r of a [*][32] tile
__device__ __forceinline__ int swz(int r, int c) {
  return r * 32 + (((c ^ (r & 3)) << 3));
}

__device__ __forceinline__ void cvt_store(u16* dst, float4 a, float4 b) {
  u32x4 v;
  v[0] = pack2(a.x, a.y); v[1] = pack2(a.z, a.w);
  v[2] = pack2(b.x, b.y); v[3] = pack2(b.z, b.w);
  *reinterpret_cast<u32x4*>(dst) = v;
}

__device__ __forceinline__ bf16x8 frag(const u16* p) {
  return __builtin_bit_cast(bf16x8, *reinterpret_cast<const u16x8*>(p));
}

__device__ __forceinline__ f32x4 mfma(bf16x8 a, bf16x8 b, f32x4 c) {
  return __builtin_amdgcn_mfma_f32_16x16x32_bf16(a, b, c, 0, 0, 0);
}

// ---------------------------------------------------------------------------
// Dispatch: bucket token-pairs by expert (order within expert arbitrary;
// output values are placement-invariant).
// ---------------------------------------------------------------------------
__global__ void moe_dispatch(const int* __restrict__ idx,
                             int* __restrict__ offs, int* __restrict__ perm) {
  __shared__ int s_cnt[NE];
  __shared__ int s_off[NE + 1];
  __shared__ int s_cur[NE];
  const int tid = threadIdx.x;
  if (tid < NE) { s_cnt[tid] = 0; s_cur[tid] = 0; }
  __syncthreads();
  for (int n = tid; n < NTOT; n += 256) atomicAdd(&s_cnt[idx[n]], 1);
  __syncthreads();
  if (tid == 0) {
    int a = 0;
    for (int e = 0; e < NE; ++e) { s_off[e] = a; a += s_cnt[e]; }
    s_off[NE] = a;
  }
  __syncthreads();
  for (int n = tid; n < NTOT; n += 256) {
    const int e = idx[n];
    perm[s_off[e] + atomicAdd(&s_cur[e], 1)] = n;
  }
  if (tid < NE + 1) offs[tid] = s_off[tid];
}

// ---------------------------------------------------------------------------
// Stage 1: h = silu(X Wg^T) * (X Wu^T), BM=128 x BN=64 (dual) x BK=32
// grid (32, 3, 8), 256 threads (4 waves; wave tile 64x32 of G and of U)
// ---------------------------------------------------------------------------
__global__ __launch_bounds__(256, 2) void moe_stage1(
    const float* __restrict__ x, const int* __restrict__ perm,
    const int* __restrict__ offs, const float* __restrict__ wg,
    const float* __restrict__ wu, u16* __restrict__ hbuf) {
  const int e = blockIdx.z;
  const int off = offs[e];
  const int cnt = offs[e + 1] - off;
  const int mt = blockIdx.y;
  if (mt * 128 >= cnt) return;
  const int nt = blockIdx.x;  // 0..31 (N=64 per matrix)

  __shared__ __align__(16) u16 sX[2][128 * 32];
  __shared__ __align__(16) u16 sG[2][64 * 32];
  __shared__ __align__(16) u16 sU[2][64 * 32];

  const int tid = threadIdx.x;
  const int lane = tid & 63;
  const int wv = tid >> 6;
  const int wm = (wv >> 1) * 64;
  const int wn = (wv & 1) * 32;

  // staging: thread -> (row = tid>>2, chunk = tid&3)
  const int sc = tid & 3;
  const int srow = tid >> 2;  // 0..63

  const int t0 = perm[min(off + mt * 128 + srow, NTOT - 1)];
  const int t1 = perm[min(off + mt * 128 + srow + 64, NTOT - 1)];
  const float* xp0 = x + (size_t)(t0 >> 1) * DDIM + sc * 8;  // TOPK=2
  const float* xp1 = x + (size_t)(t1 >> 1) * DDIM + sc * 8;
  const float* gp = wg + ((size_t)e * HDIM + nt * 64 + srow) * DDIM + sc * 8;
  const float* up = wu + ((size_t)e * HDIM + nt * 64 + srow) * DDIM + sc * 8;

  f32x4 aG[4][2] = {};
  f32x4 aU[4][2] = {};
  float4 pf0[8], pf1[8];

#define LOADS1(pf, kt) do {                                          \
    const float4* q;                                                 \
    q = (const float4*)(xp0 + (kt) * 32); pf[0] = q[0]; pf[1] = q[1];\
    q = (const float4*)(xp1 + (kt) * 32); pf[2] = q[0]; pf[3] = q[1];\
    q = (const float4*)(gp  + (kt) * 32); pf[4] = q[0]; pf[5] = q[1];\
    q = (const float4*)(up  + (kt) * 32); pf[6] = q[0]; pf[7] = q[1];\
  } while (0)

#define STORE1(pf, b) do {                                  \
    cvt_store(&sX[b][swz(srow,      sc)], pf[0], pf[1]);    \
    cvt_store(&sX[b][swz(srow + 64, sc)], pf[2], pf[3]);    \
    cvt_store(&sG[b][swz(srow,      sc)], pf[4], pf[5]);    \
    cvt_store(&sU[b][swz(srow,      sc)], pf[6], pf[7]);    \
  } while (0)

#define COMPUTE1(b) do {                                             \
    const int g = lane >> 4;                                         \
    const int fr = lane & 15;                                        \
    bf16x8 af[4], gf[2], uf[2];                                      \
    _Pragma("unroll") for (int mi = 0; mi < 4; ++mi) {               \
      const int r = wm + mi * 16 + fr;                               \
      af[mi] = frag(&sX[b][swz(r, g)]);                              \
    }                                                                \
    _Pragma("unroll") for (int ni = 0; ni < 2; ++ni) {               \
      const int r = wn + ni * 16 + fr;                               \
      gf[ni] = frag(&sG[b][swz(r, g)]);                              \
      uf[ni] = frag(&sU[b][swz(r, g)]);                              \
    }                                                                \
    _Pragma("unroll") for (int mi = 0; mi < 4; ++mi)                 \
      _Pragma("unroll") for (int ni = 0; ni < 2; ++ni) {             \
        aG[mi][ni] = mfma(af[mi], gf[ni], aG[mi][ni]);               \
        aU[mi][ni] = mfma(af[mi], uf[ni], aU[mi][ni]);               \
      }                                                              \
  } while (0)

  LOADS1(pf0, 0);
  LOADS1(pf1, 1);
  STORE1(pf0, 0);
  __syncthreads();

#pragma unroll 1
  for (int kt = 0; kt < 24; kt += 2) {
    if (kt + 2 < 24) LOADS1(pf0, kt + 2);
    COMPUTE1(0);
    STORE1(pf1, 1);
    __syncthreads();
    if (kt + 3 < 24) LOADS1(pf1, kt + 3);
    COMPUTE1(1);
    if (kt + 2 < 24) STORE1(pf0, 0);
    __syncthreads();
  }

  // epilogue: C/D layout col=lane&15, row=(lane>>4)*4+reg
  const int crow = (lane >> 4) << 2;
  const int ccol = lane & 15;
#pragma unroll
  for (int mi = 0; mi < 4; ++mi) {
#pragma unroll
    for (int ri = 0; ri < 4; ++ri) {
      const int gm = mt * 128 + wm + mi * 16 + crow + ri;
      if (gm < cnt) {
        u16* hb = hbuf + (size_t)(off + gm) * HDIM + nt * 64 + wn;
#pragma unroll
        for (int ni = 0; ni < 2; ++ni) {
          const float g = aG[mi][ni][ri];
          const float u = aU[mi][ni][ri];
          const float h = g / (1.0f + __expf(-g)) * u;
          hb[ni * 16 + ccol] = f2bf(h);
        }
      }
    }
  }
}

// ---------------------------------------------------------------------------
// Stage 2: out[tok] += h Wd^T, BM=64 x BN=128 x BK=32, split-K=2
// grid (6, 12, 8): y = ks*6 + mt. 256 threads (4 waves; wave tile 64x32)
// ---------------------------------------------------------------------------
__global__ __launch_bounds__(256, 2) void moe_stage2(
    const u16* __restrict__ hbuf, const int* __restrict__ perm,
    const int* __restrict__ offs, const float* __restrict__ wd,
    float* __restrict__ out) {
  const int e = blockIdx.z;
  const int off = offs[e];
  const int cnt = offs[e + 1] - off;
  const int mt = blockIdx.y % 6;
  const int ks = blockIdx.y / 6;
  if (mt * 64 >= cnt) return;
  const int nt = blockIdx.x;  // 0..5 (N=128)

  __shared__ __align__(16) u16 sA[2][64 * 32];
  __shared__ __align__(16) u16 sB[2][128 * 32];

  const int tid = threadIdx.x;
  const int lane = tid & 63;
  const int wv = tid >> 6;
  const int wn = wv * 32;

  const int sc = tid & 3;
  const int srow = tid >> 2;  // 0..63

  const u16* ap =
      hbuf + (size_t)min(off + mt * 64 + srow, NTOT - 1) * HDIM + ks * 1024 + sc * 8;
  const float* bp0 =
      wd + ((size_t)e * DDIM + nt * 128 + srow) * HDIM + ks * 1024 + sc * 8;
  const float* bp1 = bp0 + (size_t)64 * HDIM;

  f32x4 acc[4][2] = {};
  uint4 pa0, pa1;
  float4 pb0[4], pb1[4];

#define LOADS2(pa, pb, kt) do {                                       \
    pa = *reinterpret_cast<const uint4*>(ap + (kt) * 32);             \
    const float4* q;                                                  \
    q = (const float4*)(bp0 + (kt) * 32); pb[0] = q[0]; pb[1] = q[1]; \
    q = (const float4*)(bp1 + (kt) * 32); pb[2] = q[0]; pb[3] = q[1]; \
  } while (0)

#define STORE2(pa, pb, b) do {                                \
    *reinterpret_cast<uint4*>(&sA[b][swz(srow, sc)]) = pa;    \
    cvt_store(&sB[b][swz(srow,      sc)], pb[0], pb[1]);      \
    cvt_store(&sB[b][swz(srow + 64, sc)], pb[2], pb[3]);      \
  } while (0)

#define COMPUTE2(b) do {                                             \
    const int g = lane >> 4;                                         \
    const int fr = lane & 15;                                        \
    bf16x8 af[4], bf[2];                                             \
    _Pragma("unroll") for (int mi = 0; mi < 4; ++mi)                 \
      af[mi] = frag(&sA[b][swz(mi * 16 + fr, g)]);                   \
    _Pragma("unroll") for (int ni = 0; ni < 2; ++ni)                 \
      bf[ni] = frag(&sB[b][swz(wn + ni * 16 + fr, g)]);              \
    _Pragma("unroll") for (int mi = 0; mi < 4; ++mi)                 \
      _Pragma("unroll") for (int ni = 0; ni < 2; ++ni)               \
        acc[mi][ni] = mfma(af[mi], bf[ni], acc[mi][ni]);             \
  } while (0)

  LOADS2(pa0, pb0, 0);
  LOADS2(pa1, pb1, 1);
  STORE2(pa0, pb0, 0);
  __syncthreads();

#pragma unroll 1
  for (int kt = 0; kt < 32; kt += 2) {
    if (kt + 2 < 32) LOADS2(pa0, pb0, kt + 2);
    COMPUTE2(0);
    STORE2(pa1, pb1, 1);
    __syncthreads();
    if (kt + 3 < 32) LOADS2(pa1, pb1, kt + 3);
    COMPUTE2(1);
    if (kt + 2 < 32) STORE2(pa0, pb0, 0);
    __syncthreads();
  }

  const int crow = (lane >> 4) << 2;
  const int ccol = lane & 15;
#pragma unroll
  for (int mi = 0; mi < 4; ++mi) {
#pragma unroll
    for (int ri = 0; ri < 4; ++ri) {
      const int gm = mt * 64 + mi * 16 + crow + ri;
      if (gm < cnt) {
        const int t = perm[off + gm];
        float* orow = out + (size_t)t * DDIM + nt * 128 + wn;
#pragma unroll
        for (int ni = 0; ni < 2; ++ni) {
          atomicAdd(&orow[ni * 16 + ccol], acc[mi][ni][ri]);
        }
      }
    }
  }
}

// ---------------------------------------------------------------------------
extern "C" void kernel_launch(void* const* d_in, const int* in_sizes, int n_in,
                              void* d_out, int out_size, void* d_ws, size_t ws_size,
                              hipStream_t stream) {
  const float* x  = (const float*)d_in[0];
  const int* idx  = (const int*)d_in[1];
  const float* wg = (const float*)d_in[2];
  const float* wu = (const float*)d_in[3];
  const float* wd = (const float*)d_in[4];
  float* out = (float*)d_out;

  int* iws = (int*)d_ws;
  int* offs = iws;       // 9 ints
  int* perm = iws + 16;  // 2048 ints
  u16* hbuf = (u16*)((char*)d_ws + 16384);  // 2048*2048 bf16 = 8 MB

  hipMemsetAsync(d_out, 0, (size_t)out_size * sizeof(float), stream);
  moe_dispatch<<<1, 256, 0, stream>>>(idx, offs, perm);
  moe_stage1<<<dim3(32, 3, NE), 256, 0, stream>>>(x, perm, offs, wg, wu, hbuf);
  moe_stage2<<<dim3(6, 12, NE), 256, 0, stream>>>(hbuf, perm, offs, wd, out);
}